// Round 5
// baseline (129.845 us; speedup 1.0000x reference)
//
#include <hip/hip_runtime.h>

#define HSZ 128
#define ISZ 28
#define TSZ 28
#define CSZ 10
#define BT  16     // batch rows per block
#define NT  256    // 4 waves; wave owns TWO 16-row hidden tiles (nt=2)
#define HP  136    // h row stride in halves (272B = 68 dwords, stride-4 banks: conflict-free b128)
#define XP  40     // x row stride in halves (80B = 20 dwords, stride-20 banks: conflict-free b128)

typedef _Float16 half_t;
typedef _Float16 v8h __attribute__((ext_vector_type(8)));
typedef _Float16 v4h __attribute__((ext_vector_type(4)));
typedef float v4f __attribute__((ext_vector_type(4)));

__device__ __forceinline__ float fast_tanh(float x) {
    // 1 - 2/(e^{2x}+1); saturates correctly (+-inf -> +-1)
    float e = __expf(2.f * x);
    return 1.f - 2.f * __builtin_amdgcn_rcpf(e + 1.f);
}

// MFMA 16x16x32 f16 layouts (HW-verified):
//   A-frag: lane holds A[m = lane&15][k = (lane>>4)*8 + j], j=0..7
//   B-frag: lane holds B[k = (lane>>4)*8 + j][n = lane&15]
//   C/D   : lane holds D[row = (lane>>4)*4 + r][col = lane&15], r=0..3
// G = W · h^T: A = weight tile (rows = hidden units), B[k][n] = h[batch n][k].
// nt=2: one B read feeds two A row-tiles -> halves LDS read traffic per FLOP.
__global__ __launch_bounds__(NT, 2)
void rnn_mfma4(const float* __restrict__ x,
               const float* __restrict__ W_ih0, const float* __restrict__ W_hh0,
               const float* __restrict__ b_ih0, const float* __restrict__ b_hh0,
               const float* __restrict__ W_ih1, const float* __restrict__ W_hh1,
               const float* __restrict__ b_ih1, const float* __restrict__ b_hh1,
               const float* __restrict__ fc_w, const float* __restrict__ fc_b,
               float* __restrict__ out)
{
    __shared__ half_t h0s[2][BT * HP];
    __shared__ half_t h1s[2][BT * HP];
    __shared__ half_t xss[2][BT * XP];

    const int tid  = threadIdx.x;
    const int wave = tid >> 6;          // 0..3 -> rows [wave*32, wave*32+32) as 2 tiles
    const int lane = tid & 63;
    const int ln   = lane & 15;
    const int quad = lane >> 4;
    const int kq   = quad * 8;
    const int b0   = blockIdx.x * BT;

    // ---- persistent weight A-fragments (loaded once): 26 frags = 104 VGPR ----
    v8h aWx[2], aW0[2][4], aW1i[2][4], aW1h[2][4];
    v4f bias0[2], bias1[2];

#pragma unroll
    for (int nt = 0; nt < 2; ++nt) {
        const int base = wave * 32 + nt * 16;
        const int row  = base + ln;          // A-frag row (hidden unit)
        {
            float4 p = *(const float4*)(b_ih0 + base + quad * 4);
            float4 q = *(const float4*)(b_hh0 + base + quad * 4);
            bias0[nt] = (v4f){p.x + q.x, p.y + q.y, p.z + q.z, p.w + q.w};
            p = *(const float4*)(b_ih1 + base + quad * 4);
            q = *(const float4*)(b_hh1 + base + quad * 4);
            bias1[nt] = (v4f){p.x + q.x, p.y + q.y, p.z + q.z, p.w + q.w};
        }
        {
            const float* pw = W_ih0 + row * ISZ + kq;   // kq<=24 -> first 4 in-row
            float4 a = *(const float4*)pw;
            float4 b = (kq < 24) ? *(const float4*)(pw + 4) : make_float4(0.f, 0.f, 0.f, 0.f);
            aWx[nt] = (v8h){(half_t)a.x, (half_t)a.y, (half_t)a.z, (half_t)a.w,
                            (half_t)b.x, (half_t)b.y, (half_t)b.z, (half_t)b.w};
        }
#pragma unroll
        for (int ks = 0; ks < 4; ++ks) {
            const float4* p0 = (const float4*)(W_hh0 + row * HSZ + ks * 32 + kq);
            const float4* p1 = (const float4*)(W_ih1 + row * HSZ + ks * 32 + kq);
            const float4* p2 = (const float4*)(W_hh1 + row * HSZ + ks * 32 + kq);
            float4 a = p0[0], b = p0[1];
            aW0[nt][ks] = (v8h){(half_t)a.x, (half_t)a.y, (half_t)a.z, (half_t)a.w,
                                (half_t)b.x, (half_t)b.y, (half_t)b.z, (half_t)b.w};
            a = p1[0]; b = p1[1];
            aW1i[nt][ks] = (v8h){(half_t)a.x, (half_t)a.y, (half_t)a.z, (half_t)a.w,
                                 (half_t)b.x, (half_t)b.y, (half_t)b.z, (half_t)b.w};
            a = p2[0]; b = p2[1];
            aW1h[nt][ks] = (v8h){(half_t)a.x, (half_t)a.y, (half_t)a.z, (half_t)a.w,
                                 (half_t)b.x, (half_t)b.y, (half_t)b.z, (half_t)b.w};
        }
    }

    // ---- x staging: 512 slots (16 rows x 32 cols), 2 slots/thread ----
    const int  xm0 = tid >> 5,           xi0 = tid & 31;
    const int  xm1 = (tid + NT) >> 5,    xi1 = xi0;
    const bool xok = xi0 < ISZ;
    const float* xr0 = x + (size_t)(b0 + xm0) * (TSZ * ISZ) + xi0;
    const float* xr1 = x + (size_t)(b0 + xm1) * (TSZ * ISZ) + xi1;

    // prologue: stage x0, x1 directly; x2 -> register pipeline
    xss[0][xm0 * XP + xi0] = (half_t)(xok ? xr0[0] : 0.f);
    xss[0][xm1 * XP + xi1] = (half_t)(xok ? xr1[0] : 0.f);
    xss[1][xm0 * XP + xi0] = (half_t)(xok ? xr0[ISZ] : 0.f);
    xss[1][xm1 * XP + xi1] = (half_t)(xok ? xr1[ISZ] : 0.f);
    float xc0 = xok ? xr0[2 * ISZ] : 0.f;    // holds x(t+2) at segment t
    float xc1 = xok ? xr1[2 * ISZ] : 0.f;

    for (int idx = tid; idx < BT * HP; idx += NT)
        h1s[0][idx] = (half_t)0.f;           // h1(-1) = 0
    __syncthreads();

    // ---- h0(0) = tanh(W_ih0 x0^T + b0) -> h0s[0] ----
    {
        const v8h bx = *(const v8h*)&xss[0][ln * XP + kq];
#pragma unroll
        for (int nt = 0; nt < 2; ++nt) {
            v4f a0 = bias0[nt];
            a0 = __builtin_amdgcn_mfma_f32_16x16x32_f16(aWx[nt], bx, a0, 0, 0, 0);
            v4h p = {(half_t)fast_tanh(a0[0]), (half_t)fast_tanh(a0[1]),
                     (half_t)fast_tanh(a0[2]), (half_t)fast_tanh(a0[3])};
            *(v4h*)&h0s[0][ln * HP + wave * 32 + nt * 16 + quad * 4] = p;
        }
    }
    __syncthreads();

    // ---- main loop: segment t computes h1(t) and h0(t+1), one barrier ----
    for (int t = 0; t < TSZ - 1; ++t) {
        const int pr = t & 1;   // h0(t)->h0s[pr], h1(t-1)->h1s[pr], x(t+1)->xss[pr^1]

        // issue prefetch of x(t+3) early (in flight across the whole segment)
        float xn0 = 0.f, xn1 = 0.f;
        if (t < TSZ - 3 && xok) {
            xn0 = xr0[(t + 3) * ISZ];
            xn1 = xr1[(t + 3) * ISZ];
        }

        // B-fragments (shared by both row-tiles)
        v8h bh0[4];
#pragma unroll
        for (int ks = 0; ks < 4; ++ks)
            bh0[ks] = *(const v8h*)&h0s[pr][ln * HP + ks * 32 + kq];
        const v8h bx = *(const v8h*)&xss[pr ^ 1][ln * XP + kq];

        v4f a1[2] = {bias1[0], bias1[1]};
        v4f a0[2] = {bias0[0], bias0[1]};
#pragma unroll
        for (int nt = 0; nt < 2; ++nt)
            a0[nt] = __builtin_amdgcn_mfma_f32_16x16x32_f16(aWx[nt], bx, a0[nt], 0, 0, 0);
#pragma unroll
        for (int ks = 0; ks < 4; ++ks) {
            const v8h bh1 = *(const v8h*)&h1s[pr][ln * HP + ks * 32 + kq];
#pragma unroll
            for (int nt = 0; nt < 2; ++nt) {
                a1[nt] = __builtin_amdgcn_mfma_f32_16x16x32_f16(aW1i[nt][ks], bh0[ks], a1[nt], 0, 0, 0);
                a1[nt] = __builtin_amdgcn_mfma_f32_16x16x32_f16(aW1h[nt][ks], bh1,     a1[nt], 0, 0, 0);
                a0[nt] = __builtin_amdgcn_mfma_f32_16x16x32_f16(aW0[nt][ks],  bh0[ks], a0[nt], 0, 0, 0);
            }
        }

        // tanh + packed h writes
#pragma unroll
        for (int nt = 0; nt < 2; ++nt) {
            const int base = wave * 32 + nt * 16;
            v4h p1 = {(half_t)fast_tanh(a1[nt][0]), (half_t)fast_tanh(a1[nt][1]),
                      (half_t)fast_tanh(a1[nt][2]), (half_t)fast_tanh(a1[nt][3])};
            *(v4h*)&h1s[pr ^ 1][ln * HP + base + quad * 4] = p1;
            v4h p0 = {(half_t)fast_tanh(a0[nt][0]), (half_t)fast_tanh(a0[nt][1]),
                      (half_t)fast_tanh(a0[nt][2]), (half_t)fast_tanh(a0[nt][3])};
            *(v4h*)&h0s[pr ^ 1][ln * HP + base + quad * 4] = p0;
        }

        // write x(t+2) (loaded a full segment ago) into the freed x buffer
        if (t < TSZ - 2) {
            xss[pr][xm0 * XP + xi0] = (half_t)xc0;
            xss[pr][xm1 * XP + xi1] = (half_t)xc1;
        }
        xc0 = xn0; xc1 = xn1;

        __syncthreads();
    }

    // ---- final segment: h1(27) only -> h1s[0] ----
    {
        const int pr = (TSZ - 1) & 1;   // = 1
        v8h bh0[4];
#pragma unroll
        for (int ks = 0; ks < 4; ++ks)
            bh0[ks] = *(const v8h*)&h0s[pr][ln * HP + ks * 32 + kq];
        v4f a1[2] = {bias1[0], bias1[1]};
#pragma unroll
        for (int ks = 0; ks < 4; ++ks) {
            const v8h bh1 = *(const v8h*)&h1s[pr][ln * HP + ks * 32 + kq];
#pragma unroll
            for (int nt = 0; nt < 2; ++nt) {
                a1[nt] = __builtin_amdgcn_mfma_f32_16x16x32_f16(aW1i[nt][ks], bh0[ks], a1[nt], 0, 0, 0);
                a1[nt] = __builtin_amdgcn_mfma_f32_16x16x32_f16(aW1h[nt][ks], bh1,     a1[nt], 0, 0, 0);
            }
        }
#pragma unroll
        for (int nt = 0; nt < 2; ++nt) {
            const int base = wave * 32 + nt * 16;
            v4h p1 = {(half_t)fast_tanh(a1[nt][0]), (half_t)fast_tanh(a1[nt][1]),
                      (half_t)fast_tanh(a1[nt][2]), (half_t)fast_tanh(a1[nt][3])};
            *(v4h*)&h1s[pr ^ 1][ln * HP + base + quad * 4] = p1;
        }
    }
    __syncthreads();

    // ---- FC epilogue: out = h1(27) @ fc_w^T + fc_b ----
    if (tid < BT * CSZ) {
        const int m = tid / CSZ, cc = tid - m * CSZ;
        float s = fc_b[cc];
#pragma unroll
        for (int k8 = 0; k8 < HSZ / 8; ++k8) {
            const v8h hv = *(const v8h*)&h1s[0][m * HP + k8 * 8];
            const float4 w0 = *(const float4*)(fc_w + cc * HSZ + k8 * 8);
            const float4 w1 = *(const float4*)(fc_w + cc * HSZ + k8 * 8 + 4);
            s += (float)hv[0] * w0.x + (float)hv[1] * w0.y +
                 (float)hv[2] * w0.z + (float)hv[3] * w0.w +
                 (float)hv[4] * w1.x + (float)hv[5] * w1.y +
                 (float)hv[6] * w1.z + (float)hv[7] * w1.w;
        }
        out[(b0 + m) * CSZ + cc] = s;
    }
}

extern "C" void kernel_launch(void* const* d_in, const int* in_sizes, int n_in,
                              void* d_out, int out_size, void* d_ws, size_t ws_size,
                              hipStream_t stream) {
    const float* x     = (const float*)d_in[0];
    const float* W_ih0 = (const float*)d_in[1];
    const float* W_hh0 = (const float*)d_in[2];
    const float* b_ih0 = (const float*)d_in[3];
    const float* b_hh0 = (const float*)d_in[4];
    const float* W_ih1 = (const float*)d_in[5];
    const float* W_hh1 = (const float*)d_in[6];
    const float* b_ih1 = (const float*)d_in[7];
    const float* b_hh1 = (const float*)d_in[8];
    const float* fc_w  = (const float*)d_in[9];
    const float* fc_b  = (const float*)d_in[10];
    float* out = (float*)d_out;

    const int B = in_sizes[0] / (TSZ * ISZ);   // 8192
    dim3 grid(B / BT), block(NT);
    rnn_mfma4<<<grid, block, 0, stream>>>(x, W_ih0, W_hh0, b_ih0, b_hh0,
                                          W_ih1, W_hh1, b_ih1, b_hh1,
                                          fc_w, fc_b, out);
}

// Round 6
// 128.422 us; speedup vs baseline: 1.0111x; 1.0111x over previous
//
#include <hip/hip_runtime.h>

#define HSZ 128
#define ISZ 28
#define TSZ 28
#define CSZ 10
#define BT  16     // batch rows per block (grid 512 -> 2 blocks/CU)
#define NT  512    // 8 waves, one 16-row hidden tile each
#define HP  136    // h row stride in halves (272B; 68 dwords -> odd/4 stride, benign 2-way)
#define XP  40     // x row stride in halves (80B; stride-20 banks, conflict-free b128)

typedef _Float16 half_t;
typedef _Float16 v8h __attribute__((ext_vector_type(8)));
typedef _Float16 v4h __attribute__((ext_vector_type(4)));
typedef float v4f __attribute__((ext_vector_type(4)));

__device__ __forceinline__ float fast_tanh(float x) {
    // 1 - 2/(e^{2x}+1); saturates correctly (+-inf -> +-1)
    float e = __expf(2.f * x);
    return 1.f - 2.f * __builtin_amdgcn_rcpf(e + 1.f);
}

// MFMA 16x16x32 f16 layouts (HW-verified):
//   A-frag: lane holds A[m = lane&15][k = (lane>>4)*8 + j], j=0..7
//   B-frag: lane holds B[k = (lane>>4)*8 + j][n = lane&15]
//   C/D   : lane holds D[row = (lane>>4)*4 + r][col = lane&15], r=0..3
// G = W · h^T: A = weight tile (rows = hidden units), B[k][n] = h[batch n][k].
// Split accumulators -> 4 independent MFMA chains (3,2,4,4 deep).
__global__ __launch_bounds__(NT, 4)   // 4 waves/SIMD min -> VGPR<=128, 2 blocks/CU
void rnn_mfma5(const float* __restrict__ x,
               const float* __restrict__ W_ih0, const float* __restrict__ W_hh0,
               const float* __restrict__ b_ih0, const float* __restrict__ b_hh0,
               const float* __restrict__ W_ih1, const float* __restrict__ W_hh1,
               const float* __restrict__ b_ih1, const float* __restrict__ b_hh1,
               const float* __restrict__ fc_w, const float* __restrict__ fc_b,
               float* __restrict__ out)
{
    __shared__ half_t h0s[2][BT * HP];
    __shared__ half_t h1s[2][BT * HP];
    __shared__ half_t xss[2][BT * XP];

    const int tid  = threadIdx.x;
    const int wave = tid >> 6;          // 0..7 -> hidden rows [wave*16, wave*16+16)
    const int lane = tid & 63;
    const int ln   = lane & 15;
    const int quad = lane >> 4;
    const int kq   = quad * 8;
    const int b0   = blockIdx.x * BT;
    const int base = wave * 16;
    const int row  = base + ln;         // A-frag row (hidden unit)

    // ---- persistent weight A-fragments (loaded once): 13 frags = 52 VGPR ----
    v8h aWx, aW0[4], aW1i[4], aW1h[4];
    v4f bias0, bias1;
    {
        float4 p = *(const float4*)(b_ih0 + base + quad * 4);
        float4 q = *(const float4*)(b_hh0 + base + quad * 4);
        bias0 = (v4f){p.x + q.x, p.y + q.y, p.z + q.z, p.w + q.w};
        p = *(const float4*)(b_ih1 + base + quad * 4);
        q = *(const float4*)(b_hh1 + base + quad * 4);
        bias1 = (v4f){p.x + q.x, p.y + q.y, p.z + q.z, p.w + q.w};
    }
    {
        const float* pw = W_ih0 + row * ISZ + kq;      // kq<=24 -> first 4 in-row
        float4 a = *(const float4*)pw;
        float4 b = (kq < 24) ? *(const float4*)(pw + 4) : make_float4(0.f, 0.f, 0.f, 0.f);
        // zero-pad weights for k>=ISZ -> x pad columns may hold garbage safely
        aWx = (v8h){(half_t)a.x, (half_t)a.y, (half_t)a.z, (half_t)a.w,
                    (half_t)(kq + 4 < ISZ ? b.x : 0.f), (half_t)(kq + 5 < ISZ ? b.y : 0.f),
                    (half_t)(kq + 6 < ISZ ? b.z : 0.f), (half_t)(kq + 7 < ISZ ? b.w : 0.f)};
    }
#pragma unroll
    for (int ks = 0; ks < 4; ++ks) {
        const float4* p0 = (const float4*)(W_hh0 + row * HSZ + ks * 32 + kq);
        const float4* p1 = (const float4*)(W_ih1 + row * HSZ + ks * 32 + kq);
        const float4* p2 = (const float4*)(W_hh1 + row * HSZ + ks * 32 + kq);
        float4 a = p0[0], b = p0[1];
        aW0[ks] = (v8h){(half_t)a.x, (half_t)a.y, (half_t)a.z, (half_t)a.w,
                        (half_t)b.x, (half_t)b.y, (half_t)b.z, (half_t)b.w};
        a = p1[0]; b = p1[1];
        aW1i[ks] = (v8h){(half_t)a.x, (half_t)a.y, (half_t)a.z, (half_t)a.w,
                         (half_t)b.x, (half_t)b.y, (half_t)b.z, (half_t)b.w};
        a = p2[0]; b = p2[1];
        aW1h[ks] = (v8h){(half_t)a.x, (half_t)a.y, (half_t)a.z, (half_t)a.w,
                         (half_t)b.x, (half_t)b.y, (half_t)b.z, (half_t)b.w};
    }

    // ---- x staging: thread <-> (batch row, col); global col clamped to 27 ----
    const int xm = tid >> 5;
    const int xi = tid & 31;
    const int xiC = xi < ISZ ? xi : ISZ - 1;    // clamp: pad lanes re-read col 27
    const float* xrow = x + (size_t)(b0 + xm) * (TSZ * ISZ) + xiC;

    // prologue: stage x0, x1 directly; x2 -> register pipeline
    xss[0][xm * XP + xi] = (half_t)xrow[0];
    xss[1][xm * XP + xi] = (half_t)xrow[ISZ];
    float xc = xrow[2 * ISZ];                   // holds x(t+2) at segment t

    for (int idx = tid; idx < BT * HP; idx += NT)
        h1s[0][idx] = (half_t)0.f;              // h1(-1) = 0
    __syncthreads();

    // ---- h0(0) = tanh(W_ih0 x0^T + b0) -> h0s[0] ----
    {
        const v8h bx = *(const v8h*)&xss[0][ln * XP + kq];
        v4f a0 = bias0;
        a0 = __builtin_amdgcn_mfma_f32_16x16x32_f16(aWx, bx, a0, 0, 0, 0);
        v4h p = {(half_t)fast_tanh(a0[0]), (half_t)fast_tanh(a0[1]),
                 (half_t)fast_tanh(a0[2]), (half_t)fast_tanh(a0[3])};
        *(v4h*)&h0s[0][ln * HP + base + quad * 4] = p;
    }
    __syncthreads();

    // ---- one segment: computes h1(t) and h0(t+1); pr = t&1 compile-time ----
    auto seg = [&](int t, int pr, bool doX) __attribute__((always_inline)) {
        // prefetch x(t+3) (scalar-uniform row, clamped; in flight all segment)
        int tn = t + 3; if (tn > TSZ - 1) tn = TSZ - 1;
        const float xn = xrow[tn * ISZ];

        // B-fragments
        v8h bh0_0 = *(const v8h*)&h0s[pr][ln * HP + 0 * 32 + kq];
        v8h bh0_1 = *(const v8h*)&h0s[pr][ln * HP + 1 * 32 + kq];
        v8h bh0_2 = *(const v8h*)&h0s[pr][ln * HP + 2 * 32 + kq];
        v8h bh0_3 = *(const v8h*)&h0s[pr][ln * HP + 3 * 32 + kq];
        const v8h bx = *(const v8h*)&xss[pr ^ 1][ln * XP + kq];

        // 4 independent accumulator chains
        v4f c0 = bias0, d0 = (v4f){0.f, 0.f, 0.f, 0.f};
        v4f c1 = bias1, d1 = (v4f){0.f, 0.f, 0.f, 0.f};

        c0 = __builtin_amdgcn_mfma_f32_16x16x32_f16(aWx,      bx,    c0, 0, 0, 0);
        c1 = __builtin_amdgcn_mfma_f32_16x16x32_f16(aW1i[0],  bh0_0, c1, 0, 0, 0);
        v8h bh1_0 = *(const v8h*)&h1s[pr][ln * HP + 0 * 32 + kq];
        d1 = __builtin_amdgcn_mfma_f32_16x16x32_f16(aW1h[0],  bh1_0, d1, 0, 0, 0);
        c0 = __builtin_amdgcn_mfma_f32_16x16x32_f16(aW0[0],   bh0_0, c0, 0, 0, 0);
        d0 = __builtin_amdgcn_mfma_f32_16x16x32_f16(aW0[1],   bh0_1, d0, 0, 0, 0);
        c1 = __builtin_amdgcn_mfma_f32_16x16x32_f16(aW1i[1],  bh0_1, c1, 0, 0, 0);
        v8h bh1_1 = *(const v8h*)&h1s[pr][ln * HP + 1 * 32 + kq];
        d1 = __builtin_amdgcn_mfma_f32_16x16x32_f16(aW1h[1],  bh1_1, d1, 0, 0, 0);
        c0 = __builtin_amdgcn_mfma_f32_16x16x32_f16(aW0[2],   bh0_2, c0, 0, 0, 0);
        d0 = __builtin_amdgcn_mfma_f32_16x16x32_f16(aW0[3],   bh0_3, d0, 0, 0, 0);
        c1 = __builtin_amdgcn_mfma_f32_16x16x32_f16(aW1i[2],  bh0_2, c1, 0, 0, 0);
        v8h bh1_2 = *(const v8h*)&h1s[pr][ln * HP + 2 * 32 + kq];
        d1 = __builtin_amdgcn_mfma_f32_16x16x32_f16(aW1h[2],  bh1_2, d1, 0, 0, 0);
        c1 = __builtin_amdgcn_mfma_f32_16x16x32_f16(aW1i[3],  bh0_3, c1, 0, 0, 0);
        v8h bh1_3 = *(const v8h*)&h1s[pr][ln * HP + 3 * 32 + kq];
        d1 = __builtin_amdgcn_mfma_f32_16x16x32_f16(aW1h[3],  bh1_3, d1, 0, 0, 0);

        const v4f a0 = c0 + d0;
        const v4f a1 = c1 + d1;

        v4h p1 = {(half_t)fast_tanh(a1[0]), (half_t)fast_tanh(a1[1]),
                  (half_t)fast_tanh(a1[2]), (half_t)fast_tanh(a1[3])};
        *(v4h*)&h1s[pr ^ 1][ln * HP + base + quad * 4] = p1;
        v4h p0 = {(half_t)fast_tanh(a0[0]), (half_t)fast_tanh(a0[1]),
                  (half_t)fast_tanh(a0[2]), (half_t)fast_tanh(a0[3])};
        *(v4h*)&h0s[pr ^ 1][ln * HP + base + quad * 4] = p0;

        if (doX)
            xss[pr][xm * XP + xi] = (half_t)xc;   // x(t+2), loaded a segment ago
        xc = xn;

        __syncthreads();
    };

    // 27 main segments: 13 unrolled pairs + one single (t=26)
    for (int tp = 0; tp < 13; ++tp) {
        seg(2 * tp,     0, true);
        seg(2 * tp + 1, 1, true);
    }
    seg(26, 0, false);

    // ---- final segment (t=27, pr=1): h1(27) only -> h1s[0] ----
    {
        v4f c1 = bias1, d1 = (v4f){0.f, 0.f, 0.f, 0.f};
#pragma unroll
        for (int ks = 0; ks < 4; ++ks) {
            const v8h bh0 = *(const v8h*)&h0s[1][ln * HP + ks * 32 + kq];
            const v8h bh1 = *(const v8h*)&h1s[1][ln * HP + ks * 32 + kq];
            c1 = __builtin_amdgcn_mfma_f32_16x16x32_f16(aW1i[ks], bh0, c1, 0, 0, 0);
            d1 = __builtin_amdgcn_mfma_f32_16x16x32_f16(aW1h[ks], bh1, d1, 0, 0, 0);
        }
        const v4f a1 = c1 + d1;
        v4h p1 = {(half_t)fast_tanh(a1[0]), (half_t)fast_tanh(a1[1]),
                  (half_t)fast_tanh(a1[2]), (half_t)fast_tanh(a1[3])};
        *(v4h*)&h1s[0][ln * HP + base + quad * 4] = p1;
    }
    __syncthreads();

    // ---- FC epilogue: out = h1(27) @ fc_w^T + fc_b ----
    if (tid < BT * CSZ) {
        const int m = tid / CSZ, cc = tid - m * CSZ;
        float s = fc_b[cc];
#pragma unroll
        for (int k8 = 0; k8 < HSZ / 8; ++k8) {
            const v8h hv = *(const v8h*)&h1s[0][m * HP + k8 * 8];
            const float4 w0 = *(const float4*)(fc_w + cc * HSZ + k8 * 8);
            const float4 w1 = *(const float4*)(fc_w + cc * HSZ + k8 * 8 + 4);
            s += (float)hv[0] * w0.x + (float)hv[1] * w0.y +
                 (float)hv[2] * w0.z + (float)hv[3] * w0.w +
                 (float)hv[4] * w1.x + (float)hv[5] * w1.y +
                 (float)hv[6] * w1.z + (float)hv[7] * w1.w;
        }
        out[(b0 + m) * CSZ + cc] = s;
    }
}

extern "C" void kernel_launch(void* const* d_in, const int* in_sizes, int n_in,
                              void* d_out, int out_size, void* d_ws, size_t ws_size,
                              hipStream_t stream) {
    const float* x     = (const float*)d_in[0];
    const float* W_ih0 = (const float*)d_in[1];
    const float* W_hh0 = (const float*)d_in[2];
    const float* b_ih0 = (const float*)d_in[3];
    const float* b_hh0 = (const float*)d_in[4];
    const float* W_ih1 = (const float*)d_in[5];
    const float* W_hh1 = (const float*)d_in[6];
    const float* b_ih1 = (const float*)d_in[7];
    const float* b_hh1 = (const float*)d_in[8];
    const float* fc_w  = (const float*)d_in[9];
    const float* fc_b  = (const float*)d_in[10];
    float* out = (float*)d_out;

    const int B = in_sizes[0] / (TSZ * ISZ);   // 8192
    dim3 grid(B / BT), block(NT);
    rnn_mfma5<<<grid, block, 0, stream>>>(x, W_ih0, W_hh0, b_ih0, b_hh0,
                                          W_ih1, W_hh1, b_ih1, b_hh1,
                                          fc_w, fc_b, out);
}

// Round 8
// 127.663 us; speedup vs baseline: 1.0171x; 1.0059x over previous
//
#include <hip/hip_runtime.h>

#define HSZ 128
#define ISZ 28
#define TSZ 28
#define CSZ 10
#define BT  16     // batch rows per block (grid 512 -> 2 blocks/CU)
#define NT  512    // 8 waves, one 16-row hidden tile each
#define HP  136    // h row stride in halves
#define XP  40     // x row stride in halves

typedef _Float16 half_t;
typedef _Float16 v8h __attribute__((ext_vector_type(8)));
typedef _Float16 v4h __attribute__((ext_vector_type(4)));
typedef _Float16 v2h __attribute__((ext_vector_type(2)));
typedef __fp16   v2fp16 __attribute__((ext_vector_type(2)));
typedef float v4f __attribute__((ext_vector_type(4)));

#define MFMA16(A, B, C) __builtin_amdgcn_mfma_f32_16x16x32_f16((A), (B), (C), 0, 0, 0)

__device__ __forceinline__ float fast_tanh(float x) {
    // tanh(x) = 1 - 2/(exp2(2*log2e*x)+1); saturates correctly at +-inf
    float e = __builtin_amdgcn_exp2f(x * 2.8853900817779268f);
    return 1.f - 2.f * __builtin_amdgcn_rcpf(e + 1.f);
}

__device__ __forceinline__ v4h pack4(const v4f a) {
    v2fp16 lo = __builtin_amdgcn_cvt_pkrtz(fast_tanh(a[0]), fast_tanh(a[1]));
    v2fp16 hi = __builtin_amdgcn_cvt_pkrtz(fast_tanh(a[2]), fast_tanh(a[3]));
    v2h lo2 = __builtin_bit_cast(v2h, lo);
    v2h hi2 = __builtin_bit_cast(v2h, hi);
    return (v4h){lo2[0], lo2[1], hi2[0], hi2[1]};
}

// MFMA 16x16x32 f16 layouts (HW-verified):
//   A-frag: lane holds A[m = lane&15][k = (lane>>4)*8 + j], j=0..7
//   B-frag: lane holds B[k = (lane>>4)*8 + j][n = lane&15]
//   C/D   : lane holds D[row = (lane>>4)*4 + r][col = lane&15], r=0..3
// G = W · h^T: A = weight tile (rows = hidden units), B[k][n] = h[batch n][k].
__global__ __launch_bounds__(NT, 4)
void rnn_mfma6(const float* __restrict__ x,
               const float* __restrict__ W_ih0, const float* __restrict__ W_hh0,
               const float* __restrict__ b_ih0, const float* __restrict__ b_hh0,
               const float* __restrict__ W_ih1, const float* __restrict__ W_hh1,
               const float* __restrict__ b_ih1, const float* __restrict__ b_hh1,
               const float* __restrict__ fc_w, const float* __restrict__ fc_b,
               float* __restrict__ out)
{
    __shared__ half_t h0s[2][BT * HP];
    __shared__ half_t h1s[2][BT * HP];
    __shared__ half_t xss[2][BT * XP];

    const int tid  = threadIdx.x;
    const int wave = tid >> 6;
    const int lane = tid & 63;
    const int ln   = lane & 15;
    const int quad = lane >> 4;
    const int kq   = quad * 8;
    const int b0   = blockIdx.x * BT;
    const int base = wave * 16;
    const int row  = base + ln;

    // ---- persistent weight A-fragments (loaded once): 13 frags = 52 VGPR ----
    v8h aWx, aW0[4], aW1i[4], aW1h[4];
    v4f bias0, bias1;
    {
        float4 p = *(const float4*)(b_ih0 + base + quad * 4);
        float4 q = *(const float4*)(b_hh0 + base + quad * 4);
        bias0 = (v4f){p.x + q.x, p.y + q.y, p.z + q.z, p.w + q.w};
        p = *(const float4*)(b_ih1 + base + quad * 4);
        q = *(const float4*)(b_hh1 + base + quad * 4);
        bias1 = (v4f){p.x + q.x, p.y + q.y, p.z + q.z, p.w + q.w};
    }
    {
        const float* pw = W_ih0 + row * ISZ + kq;
        float4 a = *(const float4*)pw;
        float4 b = (kq < 24) ? *(const float4*)(pw + 4) : make_float4(0.f, 0.f, 0.f, 0.f);
        aWx = (v8h){(half_t)a.x, (half_t)a.y, (half_t)a.z, (half_t)a.w,
                    (half_t)(kq + 4 < ISZ ? b.x : 0.f), (half_t)(kq + 5 < ISZ ? b.y : 0.f),
                    (half_t)(kq + 6 < ISZ ? b.z : 0.f), (half_t)(kq + 7 < ISZ ? b.w : 0.f)};
    }
#pragma unroll
    for (int ks = 0; ks < 4; ++ks) {
        const float4* p0 = (const float4*)(W_hh0 + row * HSZ + ks * 32 + kq);
        const float4* p1 = (const float4*)(W_ih1 + row * HSZ + ks * 32 + kq);
        const float4* p2 = (const float4*)(W_hh1 + row * HSZ + ks * 32 + kq);
        float4 a = p0[0], b = p0[1];
        aW0[ks] = (v8h){(half_t)a.x, (half_t)a.y, (half_t)a.z, (half_t)a.w,
                        (half_t)b.x, (half_t)b.y, (half_t)b.z, (half_t)b.w};
        a = p1[0]; b = p1[1];
        aW1i[ks] = (v8h){(half_t)a.x, (half_t)a.y, (half_t)a.z, (half_t)a.w,
                         (half_t)b.x, (half_t)b.y, (half_t)b.z, (half_t)b.w};
        a = p2[0]; b = p2[1];
        aW1h[ks] = (v8h){(half_t)a.x, (half_t)a.y, (half_t)a.z, (half_t)a.w,
                         (half_t)b.x, (half_t)b.y, (half_t)b.z, (half_t)b.w};
    }

    // ---- anti-phase the two CU-resident blocks (CU-mates are i and i+256) ----
    if ((blockIdx.x >> 8) & 1) {
        __builtin_amdgcn_s_sleep(8);
        __builtin_amdgcn_s_sleep(8);
    }

    // ---- x staging: thread <-> (batch row, col); global col clamped ----
    const int xm = tid >> 5;
    const int xi = tid & 31;
    const int xiC = xi < ISZ ? xi : ISZ - 1;
    const float* xrow = x + (size_t)(b0 + xm) * (TSZ * ISZ) + xiC;

    xss[0][xm * XP + xi] = (half_t)xrow[0];
    xss[1][xm * XP + xi] = (half_t)xrow[ISZ];
    float xc = xrow[2 * ISZ];                   // holds x(t+2) at segment t

    for (int idx = tid; idx < BT * HP; idx += NT)
        h1s[0][idx] = (half_t)0.f;              // h1(-1) = 0
    __syncthreads();

    // ---- h0(0) = tanh(W_ih0 x0^T + b0) -> h0s[0] ----
    {
        const v8h bx = *(const v8h*)&xss[0][ln * XP + kq];
        v4f a0 = MFMA16(aWx, bx, bias0);
        *(v4h*)&h0s[0][ln * HP + base + quad * 4] = pack4(a0);
    }
    __syncthreads();

    // ---- one segment: computes h1(t) and h0(t+1); pr = t&1 compile-time ----
    auto seg = [&](int t, int pr, bool doX) __attribute__((always_inline)) {
        int tn = t + 3; if (tn > TSZ - 1) tn = TSZ - 1;
        const float xn = xrow[tn * ISZ];        // VMEM prefetch, used next segment

        const half_t* h0p = &h0s[pr][ln * HP + kq];
        const half_t* h1p = &h1s[pr][ln * HP + kq];

        // reads in consumption order (r1..r9)
        const v8h bx    = *(const v8h*)&xss[pr ^ 1][ln * XP + kq];  // r1
        const v8h bh0_0 = *(const v8h*)(h0p + 0 * 32);              // r2
        const v8h bh0_1 = *(const v8h*)(h0p + 1 * 32);              // r3
        const v8h bh1_0 = *(const v8h*)(h1p + 0 * 32);              // r4
        const v8h bh0_2 = *(const v8h*)(h0p + 2 * 32);              // r5
        const v8h bh1_1 = *(const v8h*)(h1p + 1 * 32);              // r6
        const v8h bh0_3 = *(const v8h*)(h0p + 3 * 32);              // r7
        const v8h bh1_2 = *(const v8h*)(h1p + 2 * 32);              // r8
        const v8h bh1_3 = *(const v8h*)(h1p + 3 * 32);              // r9

        // 4 accumulator chains; MFMA i needs only reads <= i+2
        v4f c0 = bias0, d0 = (v4f){0.f, 0.f, 0.f, 0.f};
        v4f c1 = bias1, d1 = (v4f){0.f, 0.f, 0.f, 0.f};
        c0 = MFMA16(aWx,     bx,    c0);   // 1  (r1)
        c1 = MFMA16(aW1i[0], bh0_0, c1);   // 2  (r2)
        c0 = MFMA16(aW0[0],  bh0_0, c0);   // 3  (r2)
        d0 = MFMA16(aW0[1],  bh0_1, d0);   // 4  (r3)
        d1 = MFMA16(aW1h[0], bh1_0, d1);   // 5  (r4)
        c1 = MFMA16(aW1i[1], bh0_1, c1);   // 6  (r3)
        c0 = MFMA16(aW0[2],  bh0_2, c0);   // 7  (r5)
        d1 = MFMA16(aW1h[1], bh1_1, d1);   // 8  (r6)
        c1 = MFMA16(aW1i[2], bh0_2, c1);   // 9  (r5)
        d0 = MFMA16(aW0[3],  bh0_3, d0);   // 10 (r7)
        d1 = MFMA16(aW1h[2], bh1_2, d1);   // 11 (r8)
        c1 = MFMA16(aW1i[3], bh0_3, c1);   // 12 (r7)
        d1 = MFMA16(aW1h[3], bh1_3, d1);   // 13 (r9)

        // pin the interleave: x VMEM first, 2 DS reads, (1 MFMA, 1 DS read) x7, 6 MFMA
        __builtin_amdgcn_sched_group_barrier(0x020, 1, 0);   // VMEM read
        __builtin_amdgcn_sched_group_barrier(0x100, 2, 0);   // DS read x2
#pragma unroll
        for (int i = 0; i < 7; ++i) {
            __builtin_amdgcn_sched_group_barrier(0x008, 1, 0);  // MFMA
            __builtin_amdgcn_sched_group_barrier(0x100, 1, 0);  // DS read
        }
        __builtin_amdgcn_sched_group_barrier(0x008, 6, 0);      // MFMA x6

        const v4f a0 = c0 + d0;
        const v4f a1 = c1 + d1;
        *(v4h*)&h1s[pr ^ 1][ln * HP + base + quad * 4] = pack4(a1);
        *(v4h*)&h0s[pr ^ 1][ln * HP + base + quad * 4] = pack4(a0);

        if (doX)
            xss[pr][xm * XP + xi] = (half_t)xc;   // x(t+2), loaded a segment ago
        xc = xn;

        __syncthreads();
    };

    for (int tp = 0; tp < 13; ++tp) {
        seg(2 * tp,     0, true);
        seg(2 * tp + 1, 1, true);
    }
    seg(26, 0, false);

    // ---- final segment (t=27, pr=1): h1(27) only -> h1s[0] ----
    {
        v4f c1 = bias1, d1 = (v4f){0.f, 0.f, 0.f, 0.f};
#pragma unroll
        for (int ks = 0; ks < 4; ++ks) {
            const v8h bh0 = *(const v8h*)&h0s[1][ln * HP + ks * 32 + kq];
            const v8h bh1 = *(const v8h*)&h1s[1][ln * HP + ks * 32 + kq];
            c1 = MFMA16(aW1i[ks], bh0, c1);
            d1 = MFMA16(aW1h[ks], bh1, d1);
        }
        const v4f a1 = c1 + d1;
        *(v4h*)&h1s[0][ln * HP + base + quad * 4] = pack4(a1);
    }
    __syncthreads();

    // ---- FC epilogue: out = h1(27) @ fc_w^T + fc_b ----
    if (tid < BT * CSZ) {
        const int m = tid / CSZ, cc = tid - m * CSZ;
        float s = fc_b[cc];
#pragma unroll
        for (int k8 = 0; k8 < HSZ / 8; ++k8) {
            const v8h hv = *(const v8h*)&h1s[0][m * HP + k8 * 8];
            const float4 w0 = *(const float4*)(fc_w + cc * HSZ + k8 * 8);
            const float4 w1 = *(const float4*)(fc_w + cc * HSZ + k8 * 8 + 4);
            s += (float)hv[0] * w0.x + (float)hv[1] * w0.y +
                 (float)hv[2] * w0.z + (float)hv[3] * w0.w +
                 (float)hv[4] * w1.x + (float)hv[5] * w1.y +
                 (float)hv[6] * w1.z + (float)hv[7] * w1.w;
        }
        out[(b0 + m) * CSZ + cc] = s;
    }
}

extern "C" void kernel_launch(void* const* d_in, const int* in_sizes, int n_in,
                              void* d_out, int out_size, void* d_ws, size_t ws_size,
                              hipStream_t stream) {
    const float* x     = (const float*)d_in[0];
    const float* W_ih0 = (const float*)d_in[1];
    const float* W_hh0 = (const float*)d_in[2];
    const float* b_ih0 = (const float*)d_in[3];
    const float* b_hh0 = (const float*)d_in[4];
    const float* W_ih1 = (const float*)d_in[5];
    const float* W_hh1 = (const float*)d_in[6];
    const float* b_ih1 = (const float*)d_in[7];
    const float* b_hh1 = (const float*)d_in[8];
    const float* fc_w  = (const float*)d_in[9];
    const float* fc_b  = (const float*)d_in[10];
    float* out = (float*)d_out;

    const int B = in_sizes[0] / (TSZ * ISZ);   // 8192
    dim3 grid(B / BT), block(NT);
    rnn_mfma6<<<grid, block, 0, stream>>>(x, W_ih0, W_hh0, b_ih0, b_hh0,
                                          W_ih1, W_hh1, b_ih1, b_hh1,
                                          fc_w, fc_b, out);
}